// Round 3
// baseline (26156.912 us; speedup 1.0000x reference)
//
#include <hip/hip_runtime.h>
#include <hip/hip_bf16.h>
#include <stdint.h>

typedef unsigned short u16;
typedef __bf16 bf16x8v __attribute__((ext_vector_type(8)));
typedef float f32x4 __attribute__((ext_vector_type(4)));

#define B_ 16
#define S_ 128
#define T1_ 127
#define E_ 512
#define H_ 1024
#define H4_ 4096
#define V_ 32000
#define NEGBIG -1e10f

__device__ __forceinline__ u16 f2bf(float f) {
    union { float f; unsigned u; } v; v.f = f;
    unsigned u = v.u;
    unsigned r = (u + 0x7fffu + ((u >> 16) & 1u)) >> 16;
    return (u16)r;
}
__device__ __forceinline__ float bf2f(u16 h) {
    union { unsigned u; float f; } v; v.u = ((unsigned)h) << 16;
    return v.f;
}
__device__ __forceinline__ float sigm(float x) { return 1.f / (1.f + expf(-x)); }

// ---------------- converts / gathers ----------------

__global__ __launch_bounds__(256) void f32_to_bf16_k(const float* __restrict__ src,
                                                     u16* __restrict__ dst, int n4) {
    int idx = blockIdx.x * 256 + threadIdx.x;
    if (idx >= n4) return;
    float4 v = ((const float4*)src)[idx];
    unsigned lo = (unsigned)f2bf(v.x) | ((unsigned)f2bf(v.y) << 16);
    unsigned hi = (unsigned)f2bf(v.z) | ((unsigned)f2bf(v.w) << 16);
    uint2 pk; pk.x = lo; pk.y = hi;
    *(uint2*)(dst + (size_t)idx * 4) = pk;
}

// read 512 fp32 from src row (stride srcStride); write 1536-wide bf16 row with
// hi at col 0, hi again at col offH2, lo at col offLo.
// A-side (activations): offH2=512,  offLo=1024  -> [Ah | Ah | Al]
// B-side (weights):     offH2=1024, offLo=512   -> [Bh | Bl | Bh]
// => dot over K=1536: Ah·Bh + Ah·Bl + Al·Bh  (fp32-accurate product)
__global__ __launch_bounds__(128) void split3_rows_k(const float* __restrict__ src,
                                                     int srcStride,
                                                     u16* __restrict__ dst, int nrows,
                                                     int offH2, int offLo) {
    int j = blockIdx.x;
    if (j >= nrows) return;
    int tid = threadIdx.x;
    float4 v = *(const float4*)(src + (size_t)j * srcStride + tid * 4);
    u16 h0 = f2bf(v.x), h1 = f2bf(v.y), h2 = f2bf(v.z), h3 = f2bf(v.w);
    u16 l0 = f2bf(v.x - bf2f(h0)), l1 = f2bf(v.y - bf2f(h1));
    u16 l2 = f2bf(v.z - bf2f(h2)), l3 = f2bf(v.w - bf2f(h3));
    uint2 ph; ph.x = (unsigned)h0 | ((unsigned)h1 << 16); ph.y = (unsigned)h2 | ((unsigned)h3 << 16);
    uint2 pl; pl.x = (unsigned)l0 | ((unsigned)l1 << 16); pl.y = (unsigned)l2 | ((unsigned)l3 << 16);
    u16* base = dst + (size_t)j * 1536 + tid * 4;
    *(uint2*)(base) = ph;
    *(uint2*)(base + offH2) = ph;
    *(uint2*)(base + offLo) = pl;
}

// A3[m] = [hi|hi|lo] of emb[tok[b][tIdx]], m = tIdx*16+b  (A-side layout)
__global__ __launch_bounds__(128) void gather_split_k(const int* __restrict__ toks,
                                                      const float* __restrict__ emb,
                                                      u16* __restrict__ A, int nrows) {
    int m = blockIdx.x;
    if (m >= nrows) return;
    int tIdx = m >> 4, b = m & 15;
    int tok = toks[b * 128 + tIdx];
    int tid = threadIdx.x;
    float4 v = *(const float4*)(emb + (size_t)tok * E_ + tid * 4);
    u16 h0 = f2bf(v.x), h1 = f2bf(v.y), h2 = f2bf(v.z), h3 = f2bf(v.w);
    u16 l0 = f2bf(v.x - bf2f(h0)), l1 = f2bf(v.y - bf2f(h1));
    u16 l2 = f2bf(v.z - bf2f(h2)), l3 = f2bf(v.w - bf2f(h3));
    uint2 ph; ph.x = (unsigned)h0 | ((unsigned)h1 << 16); ph.y = (unsigned)h2 | ((unsigned)h3 << 16);
    uint2 pl; pl.x = (unsigned)l0 | ((unsigned)l1 << 16); pl.y = (unsigned)l2 | ((unsigned)l3 << 16);
    u16* base = A + (size_t)m * 1536 + tid * 4;
    *(uint2*)(base) = ph;
    *(uint2*)(base + 512) = ph;
    *(uint2*)(base + 1024) = pl;
}

// zero h0|c|a0 (3*16384 floats contiguous) + compute mask2
__global__ __launch_bounds__(256) void init_k(float* __restrict__ zero_region,
                                              const int* __restrict__ mask,
                                              int* __restrict__ mask2) {
    int idx = blockIdx.x * 256 + threadIdx.x;  // 48*256 = 12288 float4
    float4 z = {0.f, 0.f, 0.f, 0.f};
    ((float4*)zero_region)[idx] = z;
    if (blockIdx.x == 0 && threadIdx.x < 16) {
        int b = threadIdx.x;
        int first0 = 128;
        for (int s = 0; s < 128; ++s) {
            if (mask[b * 128 + s] == 0) { first0 = s; break; }
        }
        if (first0 == 128) first0 = 0;  // argmin of all-ones = 0
        int len = first0 - 1;
        int ix = (len < 0) ? 127 : len;  // JAX negative index wraps
        for (int s = 0; s < 128; ++s) mask2[b * 128 + s] = mask[b * 128 + s];
        mask2[b * 128 + ix] = 0;
    }
}

// ---------------- bf16 MFMA GEMM (C = A * Bt^T), 128x128 tile ----------------
// MODE 0: C fp32 [M x N], C[m][n] = acc + bias1[n] + bias2[n]
// MODE 1: logits: m = t*16+b ; if t<127: out[(b*127+t)*32000 + n] = acc + bias1[n]

#define GLD_LDS(g, l) \
    __builtin_amdgcn_global_load_lds((const __attribute__((address_space(1))) void*)(g), \
                                     (__attribute__((address_space(3))) void*)(l), 16, 0, 0)

template <int MODE>
__global__ __launch_bounds__(256) void gemm_bt(const u16* __restrict__ A,
                                               const u16* __restrict__ Bt,
                                               float* __restrict__ C,
                                               const float* __restrict__ bias1,
                                               const float* __restrict__ bias2,
                                               int M, int N, int K) {
    __shared__ u16 As[128 * 32];
    __shared__ u16 Bs[128 * 32];
    const int tid = threadIdx.x;
    const int bm = blockIdx.x, bn = blockIdx.y;
    const int lane = tid & 63, w = tid >> 6;
    const int wm = (w >> 1) * 64, wn = (w & 1) * 64;
    f32x4 acc[4][4] = {};

    const int r0 = tid >> 2;       // 0..63
    const int c0 = (tid & 3) * 8;  // 0,8,16,24
    const u16* ga0 = A + (size_t)(bm * 128 + r0) * K + c0;
    const u16* ga1 = A + (size_t)(bm * 128 + 64 + r0) * K + c0;
    const u16* gb0 = Bt + (size_t)(bn * 128 + r0) * K + c0;
    const u16* gb1 = Bt + (size_t)(bn * 128 + 64 + r0) * K + c0;
    u16* lA0 = As + tid * 8;
    u16* lA1 = As + 2048 + tid * 8;
    u16* lB0 = Bs + tid * 8;
    u16* lB1 = Bs + 2048 + tid * 8;

    const int fl = lane & 15, kg = lane >> 4;

    for (int k0 = 0; k0 < K; k0 += 32) {
        __syncthreads();
        GLD_LDS(ga0 + k0, lA0);
        GLD_LDS(ga1 + k0, lA1);
        GLD_LDS(gb0 + k0, lB0);
        GLD_LDS(gb1 + k0, lB1);
        __syncthreads();
        bf16x8v af[4], bfv[4];
#pragma unroll
        for (int i = 0; i < 4; ++i)
            af[i] = *(const bf16x8v*)(As + (wm + i * 16 + fl) * 32 + kg * 8);
#pragma unroll
        for (int j = 0; j < 4; ++j)
            bfv[j] = *(const bf16x8v*)(Bs + (wn + j * 16 + fl) * 32 + kg * 8);
#pragma unroll
        for (int i = 0; i < 4; ++i)
#pragma unroll
            for (int j = 0; j < 4; ++j)
                acc[i][j] = __builtin_amdgcn_mfma_f32_16x16x32_bf16(af[i], bfv[j], acc[i][j], 0, 0, 0);
    }

    const int coll = lane & 15;
    const int rowb = (lane >> 4) * 4;
#pragma unroll
    for (int i = 0; i < 4; ++i) {
#pragma unroll
        for (int j = 0; j < 4; ++j) {
#pragma unroll
            for (int r = 0; r < 4; ++r) {
                int m = bm * 128 + wm + i * 16 + rowb + r;
                int n = bn * 128 + wn + j * 16 + coll;
                float v = acc[i][j][r];
                if (MODE == 0) {
                    if (m < M) C[(size_t)m * N + n] = v + bias1[n] + bias2[n];
                } else {
                    int tt = m >> 4, bb = m & 15;
                    if (tt < T1_) C[((size_t)bb * T1_ + tt) * V_ + n] = v + bias1[n];
                }
            }
        }
    }
}

// ---------------- recurrent steps (fp32 vector) ----------------

__global__ __launch_bounds__(256) void enc_step(const float* __restrict__ pre,
                                                const float* __restrict__ Whh,
                                                const float* __restrict__ h_in,
                                                float* __restrict__ h_out,
                                                float* __restrict__ c,
                                                float* __restrict__ enc_out, int t) {
    int bk = blockIdx.x, tid = threadIdx.x;
    int b = tid & 15, jj = tid >> 4, g = jj >> 2, dd = jj & 3;
    int d = bk * 4 + dd, j = g * 1024 + d;
    const float* wrow = Whh + (size_t)j * H_;
    const float* hv = h_in + b * H_;
    float acc = 0.f;
#pragma unroll 4
    for (int k = 0; k < H_; k += 4) {
        float4 wv = *(const float4*)(wrow + k);
        float4 xv = *(const float4*)(hv + k);
        acc += wv.x * xv.x + wv.y * xv.y + wv.z * xv.z + wv.w * xv.w;
    }
    acc += pre[(size_t)(t * 16 + b) * H4_ + j];
    __shared__ float zs[16][16];
    zs[jj][b] = acc;
    __syncthreads();
    if (tid < 64) {
        int b2 = tid & 15, dd2 = tid >> 4, d2 = bk * 4 + dd2;
        float zi = zs[dd2][b2], zf = zs[4 + dd2][b2], zg = zs[8 + dd2][b2], zo = zs[12 + dd2][b2];
        float co = c[b2 * H_ + d2];
        float c2 = sigm(zf) * co + sigm(zi) * tanhf(zg);
        float h2 = sigm(zo) * tanhf(c2);
        c[b2 * H_ + d2] = c2;
        h_out[b2 * H_ + d2] = h2;
        enc_out[((size_t)b2 * 128 + t) * H_ + d2] = h2;
    }
}

__global__ __launch_bounds__(256) void dec_step(const float* __restrict__ pre,
                                                const float* __restrict__ Whh,
                                                const float* __restrict__ WihFull,
                                                const float* __restrict__ h_in,
                                                const float* __restrict__ a_in,
                                                float* __restrict__ h_out,
                                                float* __restrict__ c, int t) {
    int bk = blockIdx.x, tid = threadIdx.x;
    int b = tid & 15, jj = tid >> 4, g = jj >> 2, dd = jj & 3;
    int d = bk * 4 + dd, j = g * 1024 + d;
    const float* wh = Whh + (size_t)j * H_;
    const float* wa = WihFull + (size_t)j * 1536 + 512;
    const float* hv = h_in + b * H_;
    const float* av = a_in + b * H_;
    float acc = 0.f;
#pragma unroll 4
    for (int k = 0; k < H_; k += 4) {
        float4 wv = *(const float4*)(wh + k);
        float4 xv = *(const float4*)(hv + k);
        acc += wv.x * xv.x + wv.y * xv.y + wv.z * xv.z + wv.w * xv.w;
    }
#pragma unroll 4
    for (int k = 0; k < H_; k += 4) {
        float4 wv = *(const float4*)(wa + k);
        float4 xv = *(const float4*)(av + k);
        acc += wv.x * xv.x + wv.y * xv.y + wv.z * xv.z + wv.w * xv.w;
    }
    acc += pre[(size_t)(t * 16 + b) * H4_ + j];
    __shared__ float zs[16][16];
    zs[jj][b] = acc;
    __syncthreads();
    if (tid < 64) {
        int b2 = tid & 15, dd2 = tid >> 4, d2 = bk * 4 + dd2;
        float zi = zs[dd2][b2], zf = zs[4 + dd2][b2], zg = zs[8 + dd2][b2], zo = zs[12 + dd2][b2];
        float co = c[b2 * H_ + d2];
        float c2 = sigm(zf) * co + sigm(zi) * tanhf(zg);
        float h2 = sigm(zo) * tanhf(c2);
        c[b2 * H_ + d2] = c2;
        h_out[b2 * H_ + d2] = h2;
    }
}

__global__ __launch_bounds__(256) void attn_step(const float* __restrict__ h2,
                                                 const float* __restrict__ enc_out,
                                                 const int* __restrict__ mask2,
                                                 float* __restrict__ ct) {
    int b = blockIdx.x, tid = threadIdx.x;
    __shared__ float hq[1024];
    __shared__ float ps[128];
    __shared__ float red[2];
    *(float4*)(hq + tid * 4) = *(const float4*)(h2 + b * H_ + tid * 4);
    __syncthreads();
    int s = tid >> 1, hf = tid & 1;
    const float* er = enc_out + ((size_t)b * 128 + s) * H_ + hf * 512;
    const float* hr = hq + hf * 512;
    float sc = 0.f;
    for (int k = 0; k < 512; k += 4) {
        float4 e = *(const float4*)(er + k);
        sc += e.x * hr[k] + e.y * hr[k + 1] + e.z * hr[k + 2] + e.w * hr[k + 3];
    }
    sc += __shfl_xor(sc, 1);
    if (hf == 0) ps[s] = (mask2[b * 128 + s] == 1) ? NEGBIG : sc;
    __syncthreads();
    if (tid < 64) {
        float m2 = fmaxf(ps[tid], ps[tid + 64]);
        for (int off = 32; off; off >>= 1) m2 = fmaxf(m2, __shfl_xor(m2, off));
        if (tid == 0) red[0] = m2;
    }
    __syncthreads();
    if (tid < 128) ps[tid] = expf(ps[tid] - red[0]);
    __syncthreads();
    if (tid < 64) {
        float s2 = ps[tid] + ps[tid + 64];
        for (int off = 32; off; off >>= 1) s2 += __shfl_xor(s2, off);
        if (tid == 0) red[1] = 1.f / s2;
    }
    __syncthreads();
    float inv = red[1];
    int d0 = tid * 4;
    float4 av = {0.f, 0.f, 0.f, 0.f};
    for (int s2 = 0; s2 < 128; ++s2) {
        float p = ps[s2] * inv;
        float4 e = *(const float4*)(enc_out + ((size_t)b * 128 + s2) * H_ + d0);
        av.x += p * e.x; av.y += p * e.y; av.z += p * e.z; av.w += p * e.w;
    }
    *(float4*)(ct + b * H_ + d0) = av;
}

__global__ __launch_bounds__(512) void a2_step(const float* __restrict__ ct,
                                               const float* __restrict__ h2,
                                               const float* __restrict__ attn_W,
                                               const float* __restrict__ attn_b,
                                               float* __restrict__ a_out,
                                               u16* __restrict__ a2bf, int t) {
    int tid = threadIdx.x, bk = blockIdx.x;
    int b = tid & 15, jj = (tid >> 4) & 15, ks = tid >> 8;
    int d = bk * 16 + jj;
    const float* wrow = attn_W + (size_t)d * 2048 + ks * 1024;
    const float* x = (ks == 0 ? ct : h2) + b * H_;
    float acc = 0.f;
#pragma unroll 4
    for (int k = 0; k < 1024; k += 4) {
        float4 wv = *(const float4*)(wrow + k);
        float4 xv = *(const float4*)(x + k);
        acc += wv.x * xv.x + wv.y * xv.y + wv.z * xv.z + wv.w * xv.w;
    }
    __shared__ float val[512];
    val[tid] = acc;
    __syncthreads();
    if (tid < 256) {
        float v = val[tid] + val[tid + 256] + attn_b[d];
        v = tanhf(v);
        a_out[b * H_ + d] = v;
        a2bf[((size_t)(t * 16 + b)) * H_ + d] = f2bf(v);
    }
}

// ---------------- orchestration ----------------

extern "C" void kernel_launch(void* const* d_in, const int* in_sizes, int n_in,
                              void* d_out, int out_size, void* d_ws, size_t ws_size,
                              hipStream_t stream) {
    const int* in_tok = (const int*)d_in[0];
    const int* out_tok = (const int*)d_in[1];
    const int* mask = (const int*)d_in[2];
    const float* emb_in = (const float*)d_in[3];
    const float* emb_out = (const float*)d_in[4];
    const float* enc_Wih = (const float*)d_in[5];
    const float* enc_Whh = (const float*)d_in[6];
    const float* enc_bih = (const float*)d_in[7];
    const float* enc_bhh = (const float*)d_in[8];
    const float* dec_Wih = (const float*)d_in[9];
    const float* dec_Whh = (const float*)d_in[10];
    const float* dec_bih = (const float*)d_in[11];
    const float* dec_bhh = (const float*)d_in[12];
    const float* attn_W = (const float*)d_in[13];
    const float* attn_b = (const float*)d_in[14];
    const float* out_W = (const float*)d_in[15];
    const float* out_b = (const float*)d_in[16];
    float* out = (float*)d_out;

    char* p = (char*)d_ws;
    auto alloc = [&](size_t bytes) {
        char* r = p;
        p += (bytes + 255) & ~(size_t)255;
        return r;
    };
    u16* A_enc3 = (u16*)alloc((size_t)2048 * 1536 * 2);
    u16* A_dec3 = (u16*)alloc((size_t)2048 * 1536 * 2);
    u16* W_e3 = (u16*)alloc((size_t)4096 * 1536 * 2);
    u16* W_d3 = (u16*)alloc((size_t)4096 * 1536 * 2);
    u16* Wo = (u16*)alloc((size_t)32000 * 1024 * 2);
    float* enc_pre = (float*)alloc((size_t)2048 * 4096 * 4);
    float* dec_pre = (float*)alloc((size_t)2048 * 4096 * 4);
    float* enc_out = (float*)alloc((size_t)16 * 128 * 1024 * 4);
    u16* a2bf = (u16*)alloc((size_t)2048 * 1024 * 2);
    float* h0 = (float*)alloc(16 * 1024 * 4);
    float* c = (float*)alloc(16 * 1024 * 4);
    float* a0 = (float*)alloc(16 * 1024 * 4);
    float* h1 = (float*)alloc(16 * 1024 * 4);
    float* a1 = (float*)alloc(16 * 1024 * 4);
    float* ct = (float*)alloc(16 * 1024 * 4);
    int* mask2 = (int*)alloc(16 * 128 * 4);

    init_k<<<48, 256, 0, stream>>>(h0, mask, mask2);

    // split conversions: A-side [hi|hi|lo], B-side (weights) [hi|lo|hi]
    split3_rows_k<<<4096, 128, 0, stream>>>(enc_Wih, 512, W_e3, 4096, 1024, 512);
    split3_rows_k<<<4096, 128, 0, stream>>>(dec_Wih, 1536, W_d3, 4096, 1024, 512);
    f32_to_bf16_k<<<32000, 256, 0, stream>>>(out_W, Wo, 32000 * 1024 / 4);
    gather_split_k<<<2048, 128, 0, stream>>>(in_tok, emb_in, A_enc3, 2048);
    gather_split_k<<<2032, 128, 0, stream>>>(out_tok, emb_out, A_dec3, 2032);

    // batched input-side GEMMs at ~fp32 precision via K-tripled split-bf16
    gemm_bt<0><<<dim3(16, 32), 256, 0, stream>>>(A_enc3, W_e3, enc_pre, enc_bih, enc_bhh,
                                                 2048, 4096, 1536);
    gemm_bt<0><<<dim3(16, 32), 256, 0, stream>>>(A_dec3, W_d3, dec_pre, dec_bih, dec_bhh,
                                                 2048, 4096, 1536);

    // encoder recurrence
    float* hb[2] = {h0, h1};
    for (int t = 0; t < 128; ++t)
        enc_step<<<256, 256, 0, stream>>>(enc_pre, enc_Whh, hb[t & 1], hb[(t + 1) & 1], c,
                                          enc_out, t);

    // decoder recurrence
    float* ab[2] = {a0, a1};
    for (int t = 0; t < T1_; ++t) {
        dec_step<<<256, 256, 0, stream>>>(dec_pre, dec_Whh, dec_Wih, hb[t & 1], ab[t & 1],
                                          hb[(t + 1) & 1], c, t);
        attn_step<<<16, 256, 0, stream>>>(hb[(t + 1) & 1], enc_out, mask2, ct);
        a2_step<<<64, 512, 0, stream>>>(ct, hb[(t + 1) & 1], attn_W, attn_b, ab[(t + 1) & 1],
                                        a2bf, t);
    }

    // batched logits GEMM (bf16 is numerically safe here: no feedback path)
    gemm_bt<1><<<dim3(16, 250), 256, 0, stream>>>(a2bf, Wo, out, out_b, nullptr,
                                                  2048, 32000, 1024);
}

// Round 4
// 6858.448 us; speedup vs baseline: 3.8138x; 3.8138x over previous
//
#include <hip/hip_runtime.h>
#include <hip/hip_bf16.h>
#include <stdint.h>

typedef unsigned short u16;
typedef __bf16 bf16x8v __attribute__((ext_vector_type(8)));
typedef float f32x4 __attribute__((ext_vector_type(4)));

#define B_ 16
#define S_ 128
#define T1_ 127
#define E_ 512
#define H_ 1024
#define H4_ 4096
#define V_ 32000
#define NEGBIG -1e10f

__device__ __forceinline__ u16 f2bf(float f) {
    union { float f; unsigned u; } v; v.f = f;
    unsigned u = v.u;
    unsigned r = (u + 0x7fffu + ((u >> 16) & 1u)) >> 16;
    return (u16)r;
}
__device__ __forceinline__ float bf2f(u16 h) {
    union { unsigned u; float f; } v; v.u = ((unsigned)h) << 16;
    return v.f;
}
__device__ __forceinline__ float sigm(float x) { return 1.f / (1.f + expf(-x)); }
__device__ __forceinline__ float dot4(float4 a, float4 b) {
    return a.x * b.x + a.y * b.y + a.z * b.z + a.w * b.w;
}

// ---------------- converts / gathers (unchanged, verified) ----------------

__global__ __launch_bounds__(256) void f32_to_bf16_k(const float* __restrict__ src,
                                                     u16* __restrict__ dst, int n4) {
    int idx = blockIdx.x * 256 + threadIdx.x;
    if (idx >= n4) return;
    float4 v = ((const float4*)src)[idx];
    unsigned lo = (unsigned)f2bf(v.x) | ((unsigned)f2bf(v.y) << 16);
    unsigned hi = (unsigned)f2bf(v.z) | ((unsigned)f2bf(v.w) << 16);
    uint2 pk; pk.x = lo; pk.y = hi;
    *(uint2*)(dst + (size_t)idx * 4) = pk;
}

__global__ __launch_bounds__(128) void split3_rows_k(const float* __restrict__ src,
                                                     int srcStride,
                                                     u16* __restrict__ dst, int nrows,
                                                     int offH2, int offLo) {
    int j = blockIdx.x;
    if (j >= nrows) return;
    int tid = threadIdx.x;
    float4 v = *(const float4*)(src + (size_t)j * srcStride + tid * 4);
    u16 h0 = f2bf(v.x), h1 = f2bf(v.y), h2 = f2bf(v.z), h3 = f2bf(v.w);
    u16 l0 = f2bf(v.x - bf2f(h0)), l1 = f2bf(v.y - bf2f(h1));
    u16 l2 = f2bf(v.z - bf2f(h2)), l3 = f2bf(v.w - bf2f(h3));
    uint2 ph; ph.x = (unsigned)h0 | ((unsigned)h1 << 16); ph.y = (unsigned)h2 | ((unsigned)h3 << 16);
    uint2 pl; pl.x = (unsigned)l0 | ((unsigned)l1 << 16); pl.y = (unsigned)l2 | ((unsigned)l3 << 16);
    u16* base = dst + (size_t)j * 1536 + tid * 4;
    *(uint2*)(base) = ph;
    *(uint2*)(base + offH2) = ph;
    *(uint2*)(base + offLo) = pl;
}

__global__ __launch_bounds__(128) void gather_split_k(const int* __restrict__ toks,
                                                      const float* __restrict__ emb,
                                                      u16* __restrict__ A, int nrows) {
    int m = blockIdx.x;
    if (m >= nrows) return;
    int tIdx = m >> 4, b = m & 15;
    int tok = toks[b * 128 + tIdx];
    int tid = threadIdx.x;
    float4 v = *(const float4*)(emb + (size_t)tok * E_ + tid * 4);
    u16 h0 = f2bf(v.x), h1 = f2bf(v.y), h2 = f2bf(v.z), h3 = f2bf(v.w);
    u16 l0 = f2bf(v.x - bf2f(h0)), l1 = f2bf(v.y - bf2f(h1));
    u16 l2 = f2bf(v.z - bf2f(h2)), l3 = f2bf(v.w - bf2f(h3));
    uint2 ph; ph.x = (unsigned)h0 | ((unsigned)h1 << 16); ph.y = (unsigned)h2 | ((unsigned)h3 << 16);
    uint2 pl; pl.x = (unsigned)l0 | ((unsigned)l1 << 16); pl.y = (unsigned)l2 | ((unsigned)l3 << 16);
    u16* base = A + (size_t)m * 1536 + tid * 4;
    *(uint2*)(base) = ph;
    *(uint2*)(base + 512) = ph;
    *(uint2*)(base + 1024) = pl;
}

__global__ __launch_bounds__(256) void init_k(float* __restrict__ zero_region,
                                              const int* __restrict__ mask,
                                              int* __restrict__ mask2) {
    int idx = blockIdx.x * 256 + threadIdx.x;
    float4 z = {0.f, 0.f, 0.f, 0.f};
    ((float4*)zero_region)[idx] = z;
    if (blockIdx.x == 0 && threadIdx.x < 16) {
        int b = threadIdx.x;
        int first0 = 128;
        for (int s = 0; s < 128; ++s) {
            if (mask[b * 128 + s] == 0) { first0 = s; break; }
        }
        if (first0 == 128) first0 = 0;
        int len = first0 - 1;
        int ix = (len < 0) ? 127 : len;
        for (int s = 0; s < 128; ++s) mask2[b * 128 + s] = mask[b * 128 + s];
        mask2[b * 128 + ix] = 0;
    }
}

// ---------------- bf16 MFMA GEMM (unchanged, verified) ----------------

#define GLD_LDS(g, l) \
    __builtin_amdgcn_global_load_lds((const __attribute__((address_space(1))) void*)(g), \
                                     (__attribute__((address_space(3))) void*)(l), 16, 0, 0)

template <int MODE>
__global__ __launch_bounds__(256) void gemm_bt(const u16* __restrict__ A,
                                               const u16* __restrict__ Bt,
                                               float* __restrict__ C,
                                               const float* __restrict__ bias1,
                                               const float* __restrict__ bias2,
                                               int M, int N, int K) {
    __shared__ u16 As[128 * 32];
    __shared__ u16 Bs[128 * 32];
    const int tid = threadIdx.x;
    const int bm = blockIdx.x, bn = blockIdx.y;
    const int lane = tid & 63, w = tid >> 6;
    const int wm = (w >> 1) * 64, wn = (w & 1) * 64;
    f32x4 acc[4][4] = {};

    const int r0 = tid >> 2;
    const int c0 = (tid & 3) * 8;
    const u16* ga0 = A + (size_t)(bm * 128 + r0) * K + c0;
    const u16* ga1 = A + (size_t)(bm * 128 + 64 + r0) * K + c0;
    const u16* gb0 = Bt + (size_t)(bn * 128 + r0) * K + c0;
    const u16* gb1 = Bt + (size_t)(bn * 128 + 64 + r0) * K + c0;
    u16* lA0 = As + tid * 8;
    u16* lA1 = As + 2048 + tid * 8;
    u16* lB0 = Bs + tid * 8;
    u16* lB1 = Bs + 2048 + tid * 8;

    const int fl = lane & 15, kg = lane >> 4;

    for (int k0 = 0; k0 < K; k0 += 32) {
        __syncthreads();
        GLD_LDS(ga0 + k0, lA0);
        GLD_LDS(ga1 + k0, lA1);
        GLD_LDS(gb0 + k0, lB0);
        GLD_LDS(gb1 + k0, lB1);
        __syncthreads();
        bf16x8v af[4], bfv[4];
#pragma unroll
        for (int i = 0; i < 4; ++i)
            af[i] = *(const bf16x8v*)(As + (wm + i * 16 + fl) * 32 + kg * 8);
#pragma unroll
        for (int j = 0; j < 4; ++j)
            bfv[j] = *(const bf16x8v*)(Bs + (wn + j * 16 + fl) * 32 + kg * 8);
#pragma unroll
        for (int i = 0; i < 4; ++i)
#pragma unroll
            for (int j = 0; j < 4; ++j)
                acc[i][j] = __builtin_amdgcn_mfma_f32_16x16x32_bf16(af[i], bfv[j], acc[i][j], 0, 0, 0);
    }

    const int coll = lane & 15;
    const int rowb = (lane >> 4) * 4;
#pragma unroll
    for (int i = 0; i < 4; ++i) {
#pragma unroll
        for (int j = 0; j < 4; ++j) {
#pragma unroll
            for (int r = 0; r < 4; ++r) {
                int m = bm * 128 + wm + i * 16 + rowb + r;
                int n = bn * 128 + wn + j * 16 + coll;
                float v = acc[i][j][r];
                if (MODE == 0) {
                    if (m < M) C[(size_t)m * N + n] = v + bias1[n] + bias2[n];
                } else {
                    int tt = m >> 4, bb = m & 15;
                    if (tt < T1_) C[((size_t)bb * T1_ + tt) * V_ + n] = v + bias1[n];
                }
            }
        }
    }
}

// ---------------- recurrent steps, v2: block-per-d, 4-wave k-split ----------------
// Pattern: wave wv reduces k-slice; lanes read coalesced w float4s; 16-batch
// partials in regs; LDS transpose reduce; gates fused. fp32 throughout.

// encoder: K=1024, wave k-quarter = 256 (lane float4 at wv*256+lane*4)
__global__ __launch_bounds__(256) void enc_step(const float* __restrict__ pre,
                                                const float* __restrict__ Whh,
                                                const float* __restrict__ h_in,
                                                float* __restrict__ h_out,
                                                float* __restrict__ c,
                                                float* __restrict__ enc_out, int t) {
    __shared__ float4 red4[4 * 64 * 17];  // [wave][lane][b] of gate-float4
    __shared__ float zred[256];           // [wq][v=b*4+g]
    const int d = blockIdx.x;
    const int tid = threadIdx.x;
    const int wv = tid >> 6, lane = tid & 63;
    const int k0 = wv * 256 + lane * 4;

    float4 wr[4];
#pragma unroll
    for (int g = 0; g < 4; ++g)
        wr[g] = *(const float4*)(Whh + (size_t)(g * 1024 + d) * H_ + k0);

    float4 part[16];
#pragma unroll
    for (int b = 0; b < 16; ++b) part[b] = make_float4(0.f, 0.f, 0.f, 0.f);
#pragma unroll
    for (int b = 0; b < 16; ++b) {
        float4 hv = *(const float4*)(h_in + b * H_ + k0);
        part[b].x += dot4(wr[0], hv);
        part[b].y += dot4(wr[1], hv);
        part[b].z += dot4(wr[2], hv);
        part[b].w += dot4(wr[3], hv);
    }
#pragma unroll
    for (int b = 0; b < 16; ++b) red4[(wv * 64 + lane) * 17 + b] = part[b];
    __syncthreads();
    {
        int v = tid & 63, wq = tid >> 6;
        const float* rf = (const float*)red4;
        float s = 0.f;
#pragma unroll 8
        for (int l = 0; l < 64; ++l) s += rf[(wq * 64 + l) * 68 + v];
        zred[wq * 64 + v] = s;
    }
    __syncthreads();
    if (tid < 16) {
        int b = tid;
        float zz[4];
#pragma unroll
        for (int g = 0; g < 4; ++g) {
            float s = zred[b * 4 + g] + zred[64 + b * 4 + g] + zred[128 + b * 4 + g] +
                      zred[192 + b * 4 + g];
            zz[g] = s + pre[(size_t)(t * 16 + b) * H4_ + g * 1024 + d];
        }
        float co = c[b * H_ + d];
        float c2 = sigm(zz[1]) * co + sigm(zz[0]) * tanhf(zz[2]);
        float h2 = sigm(zz[3]) * tanhf(c2);
        c[b * H_ + d] = c2;
        h_out[b * H_ + d] = h2;
        enc_out[((size_t)b * 128 + t) * H_ + d] = h2;
    }
}

// decoder LSTM: K=2048 ([h | a]); waves 0,1 -> h halves; 2,3 -> a halves.
// Wa = dec_Wih cols [512,1536). Also zeroes ct for this step's attention.
__global__ __launch_bounds__(256) void dec_step(const float* __restrict__ pre,
                                                const float* __restrict__ Whh,
                                                const float* __restrict__ WihFull,
                                                const float* __restrict__ h_in,
                                                const float* __restrict__ a_in,
                                                float* __restrict__ h_out,
                                                float* __restrict__ c,
                                                float* __restrict__ ct, int t) {
    __shared__ float4 red4[4 * 64 * 17];
    __shared__ float zred[256];
    const int d = blockIdx.x;
    const int tid = threadIdx.x;
    const int wv = tid >> 6, lane = tid & 63;
    const int kq = (wv & 1) * 512 + lane * 8;  // slice within the 1024-wide source
    const bool isA = wv >= 2;

    float4 wr[4][2];
#pragma unroll
    for (int g = 0; g < 4; ++g) {
        int j = g * 1024 + d;
        const float* wsrc = isA ? (WihFull + (size_t)j * 1536 + 512 + kq)
                                : (Whh + (size_t)j * H_ + kq);
        wr[g][0] = *(const float4*)(wsrc);
        wr[g][1] = *(const float4*)(wsrc + 4);
    }
    const float* xsrc = (isA ? a_in : h_in);

    float4 part[16];
#pragma unroll
    for (int b = 0; b < 16; ++b) part[b] = make_float4(0.f, 0.f, 0.f, 0.f);
#pragma unroll
    for (int b = 0; b < 16; ++b) {
        float4 x0 = *(const float4*)(xsrc + b * H_ + kq);
        float4 x1 = *(const float4*)(xsrc + b * H_ + kq + 4);
        part[b].x += dot4(wr[0][0], x0) + dot4(wr[0][1], x1);
        part[b].y += dot4(wr[1][0], x0) + dot4(wr[1][1], x1);
        part[b].z += dot4(wr[2][0], x0) + dot4(wr[2][1], x1);
        part[b].w += dot4(wr[3][0], x0) + dot4(wr[3][1], x1);
    }
#pragma unroll
    for (int b = 0; b < 16; ++b) red4[(wv * 64 + lane) * 17 + b] = part[b];
    __syncthreads();
    {
        int v = tid & 63, wq = tid >> 6;
        const float* rf = (const float*)red4;
        float s = 0.f;
#pragma unroll 8
        for (int l = 0; l < 64; ++l) s += rf[(wq * 64 + l) * 68 + v];
        zred[wq * 64 + v] = s;
    }
    __syncthreads();
    if (tid < 16) {
        int b = tid;
        float zz[4];
#pragma unroll
        for (int g = 0; g < 4; ++g) {
            float s = zred[b * 4 + g] + zred[64 + b * 4 + g] + zred[128 + b * 4 + g] +
                      zred[192 + b * 4 + g];
            zz[g] = s + pre[(size_t)(t * 16 + b) * H4_ + g * 1024 + d];
        }
        float co = c[b * H_ + d];
        float c2 = sigm(zz[1]) * co + sigm(zz[0]) * tanhf(zz[2]);
        float h2 = sigm(zz[3]) * tanhf(c2);
        c[b * H_ + d] = c2;
        h_out[b * H_ + d] = h2;
    } else if (tid < 32) {
        ct[(size_t)(tid - 16) * H_ + d] = 0.f;  // zero ct for attn's atomicAdd
    }
}

// attention: grid (16 b, 8 s-groups). Each block computes full scores+softmax
// (redundant x8, L2-hot) then accumulates its 16-s slice of ct via atomicAdd.
__global__ __launch_bounds__(256) void attn_step(const float* __restrict__ h2,
                                                 const float* __restrict__ enc_out,
                                                 const int* __restrict__ mask2,
                                                 float* __restrict__ ct) {
    int b = blockIdx.x, tid = threadIdx.x;
    __shared__ float hq[1024];
    __shared__ float ps[128];
    __shared__ float red[2];
    *(float4*)(hq + tid * 4) = *(const float4*)(h2 + b * H_ + tid * 4);
    __syncthreads();
    int s = tid >> 1, hf = tid & 1;
    const float* er = enc_out + ((size_t)b * 128 + s) * H_ + hf * 512;
    const float* hr = hq + hf * 512;
    float sc = 0.f;
    for (int k = 0; k < 512; k += 4) {
        float4 e = *(const float4*)(er + k);
        sc += e.x * hr[k] + e.y * hr[k + 1] + e.z * hr[k + 2] + e.w * hr[k + 3];
    }
    sc += __shfl_xor(sc, 1);
    if (hf == 0) ps[s] = (mask2[b * 128 + s] == 1) ? NEGBIG : sc;
    __syncthreads();
    if (tid < 64) {
        float m2 = fmaxf(ps[tid], ps[tid + 64]);
        for (int off = 32; off; off >>= 1) m2 = fmaxf(m2, __shfl_xor(m2, off));
        if (tid == 0) red[0] = m2;
    }
    __syncthreads();
    if (tid < 128) ps[tid] = expf(ps[tid] - red[0]);
    __syncthreads();
    if (tid < 64) {
        float s2 = ps[tid] + ps[tid + 64];
        for (int off = 32; off; off >>= 1) s2 += __shfl_xor(s2, off);
        if (tid == 0) red[1] = 1.f / s2;
    }
    __syncthreads();
    float inv = red[1];
    int sg0 = blockIdx.y * 16;
    int d0 = tid * 4;
    float4 av = {0.f, 0.f, 0.f, 0.f};
#pragma unroll
    for (int s2 = 0; s2 < 16; ++s2) {
        float p = ps[sg0 + s2] * inv;
        float4 e = *(const float4*)(enc_out + ((size_t)b * 128 + sg0 + s2) * H_ + d0);
        av.x += p * e.x; av.y += p * e.y; av.z += p * e.z; av.w += p * e.w;
    }
    atomicAdd(&ct[b * H_ + d0 + 0], av.x);
    atomicAdd(&ct[b * H_ + d0 + 1], av.y);
    atomicAdd(&ct[b * H_ + d0 + 2], av.z);
    atomicAdd(&ct[b * H_ + d0 + 3], av.w);
}

// a2: block-per-d, K=2048 ([ct | h2]); waves 0,1 -> ct halves; 2,3 -> h2.
__global__ __launch_bounds__(256) void a2_step(const float* __restrict__ ct,
                                               const float* __restrict__ h2,
                                               const float* __restrict__ attn_W,
                                               const float* __restrict__ attn_b,
                                               float* __restrict__ a_out,
                                               u16* __restrict__ a2bf, int t) {
    __shared__ float4 red4[4 * 64 * 5];  // [wave][lane][b-float4 x4]
    __shared__ float zred[64];
    const int d = blockIdx.x;
    const int tid = threadIdx.x;
    const int wv = tid >> 6, lane = tid & 63;
    const int kq = (wv & 1) * 512 + lane * 8;
    const bool isH = wv >= 2;

    const float* wsrc = attn_W + (size_t)d * 2048 + (isH ? 1024 : 0) + kq;
    float4 w0 = *(const float4*)(wsrc);
    float4 w1 = *(const float4*)(wsrc + 4);
    const float* xsrc = (isH ? h2 : ct);

    float part[16];
#pragma unroll
    for (int b = 0; b < 16; ++b) {
        float4 x0 = *(const float4*)(xsrc + b * H_ + kq);
        float4 x1 = *(const float4*)(xsrc + b * H_ + kq + 4);
        part[b] = dot4(w0, x0) + dot4(w1, x1);
    }
#pragma unroll
    for (int q = 0; q < 4; ++q) {
        float4 pk = make_float4(part[q * 4], part[q * 4 + 1], part[q * 4 + 2], part[q * 4 + 3]);
        red4[(wv * 64 + lane) * 5 + q] = pk;
    }
    __syncthreads();
    if (tid < 64) {
        int v = tid & 15, wq = tid >> 4;
        const float* rf = (const float*)red4;
        float s = 0.f;
#pragma unroll 8
        for (int l = 0; l < 64; ++l) s += rf[(wq * 64 + l) * 20 + v];
        zred[wq * 16 + v] = s;
    }
    __syncthreads();
    if (tid < 16) {
        int b = tid;
        float v = zred[b] + zred[16 + b] + zred[32 + b] + zred[48 + b] + attn_b[d];
        v = tanhf(v);
        a_out[b * H_ + d] = v;
        a2bf[((size_t)(t * 16 + b)) * H_ + d] = f2bf(v);
    }
}

// ---------------- orchestration ----------------

extern "C" void kernel_launch(void* const* d_in, const int* in_sizes, int n_in,
                              void* d_out, int out_size, void* d_ws, size_t ws_size,
                              hipStream_t stream) {
    const int* in_tok = (const int*)d_in[0];
    const int* out_tok = (const int*)d_in[1];
    const int* mask = (const int*)d_in[2];
    const float* emb_in = (const float*)d_in[3];
    const float* emb_out = (const float*)d_in[4];
    const float* enc_Wih = (const float*)d_in[5];
    const float* enc_Whh = (const float*)d_in[6];
    const float* enc_bih = (const float*)d_in[7];
    const float* enc_bhh = (const float*)d_in[8];
    const float* dec_Wih = (const float*)d_in[9];
    const float* dec_Whh = (const float*)d_in[10];
    const float* dec_bih = (const float*)d_in[11];
    const float* dec_bhh = (const float*)d_in[12];
    const float* attn_W = (const float*)d_in[13];
    const float* attn_b = (const float*)d_in[14];
    const float* out_W = (const float*)d_in[15];
    const float* out_b = (const float*)d_in[16];
    float* out = (float*)d_out;

    char* p = (char*)d_ws;
    auto alloc = [&](size_t bytes) {
        char* r = p;
        p += (bytes + 255) & ~(size_t)255;
        return r;
    };
    u16* A_enc3 = (u16*)alloc((size_t)2048 * 1536 * 2);
    u16* A_dec3 = (u16*)alloc((size_t)2048 * 1536 * 2);
    u16* W_e3 = (u16*)alloc((size_t)4096 * 1536 * 2);
    u16* W_d3 = (u16*)alloc((size_t)4096 * 1536 * 2);
    u16* Wo = (u16*)alloc((size_t)32000 * 1024 * 2);
    float* enc_pre = (float*)alloc((size_t)2048 * 4096 * 4);
    float* dec_pre = (float*)alloc((size_t)2048 * 4096 * 4);
    float* enc_out = (float*)alloc((size_t)16 * 128 * 1024 * 4);
    u16* a2bf = (u16*)alloc((size_t)2048 * 1024 * 2);
    float* h0 = (float*)alloc(16 * 1024 * 4);
    float* c = (float*)alloc(16 * 1024 * 4);
    float* a0 = (float*)alloc(16 * 1024 * 4);
    float* h1 = (float*)alloc(16 * 1024 * 4);
    float* a1 = (float*)alloc(16 * 1024 * 4);
    float* ct = (float*)alloc(16 * 1024 * 4);
    int* mask2 = (int*)alloc(16 * 128 * 4);

    init_k<<<48, 256, 0, stream>>>(h0, mask, mask2);

    split3_rows_k<<<4096, 128, 0, stream>>>(enc_Wih, 512, W_e3, 4096, 1024, 512);
    split3_rows_k<<<4096, 128, 0, stream>>>(dec_Wih, 1536, W_d3, 4096, 1024, 512);
    f32_to_bf16_k<<<32000, 256, 0, stream>>>(out_W, Wo, 32000 * 1024 / 4);
    gather_split_k<<<2048, 128, 0, stream>>>(in_tok, emb_in, A_enc3, 2048);
    gather_split_k<<<2032, 128, 0, stream>>>(out_tok, emb_out, A_dec3, 2032);

    gemm_bt<0><<<dim3(16, 32), 256, 0, stream>>>(A_enc3, W_e3, enc_pre, enc_bih, enc_bhh,
                                                 2048, 4096, 1536);
    gemm_bt<0><<<dim3(16, 32), 256, 0, stream>>>(A_dec3, W_d3, dec_pre, dec_bih, dec_bhh,
                                                 2048, 4096, 1536);

    float* hb[2] = {h0, h1};
    for (int t = 0; t < 128; ++t)
        enc_step<<<1024, 256, 0, stream>>>(enc_pre, enc_Whh, hb[t & 1], hb[(t + 1) & 1], c,
                                           enc_out, t);

    float* ab[2] = {a0, a1};
    for (int t = 0; t < T1_; ++t) {
        dec_step<<<1024, 256, 0, stream>>>(dec_pre, dec_Whh, dec_Wih, hb[t & 1], ab[t & 1],
                                           hb[(t + 1) & 1], c, ct, t);
        attn_step<<<dim3(16, 8), 256, 0, stream>>>(hb[(t + 1) & 1], enc_out, mask2, ct);
        a2_step<<<1024, 256, 0, stream>>>(ct, hb[(t + 1) & 1], attn_W, attn_b,
                                          ab[(t + 1) & 1], a2bf, t);
    }

    gemm_bt<1><<<dim3(16, 250), 256, 0, stream>>>(a2bf, Wo, out, out_b, nullptr,
                                                  2048, 32000, 1024);
}